// Round 1
// baseline (313.714 us; speedup 1.0000x reference)
//
#include <hip/hip_runtime.h>
#include <hip/hip_bf16.h>

// Problem dims (compile-time constants from the reference)
#define BB 32
#define SS 128
#define PP 64
#define DD 256
#define HH 128
#define NF 3

// ---------------------------------------------------------------------------
// Kernel 1: conv-attention pooling over the pad dim.
// One block per (b,s). Stage [64][256] fp32 tile in LDS (64 KiB) so HBM is
// read exactly once. scores -> softmax(P) -> weighted sum over P.
// ---------------------------------------------------------------------------
__global__ __launch_bounds__(256) void k_pool(
    const float* __restrict__ inp,      // [B,S,P,D]
    const float* __restrict__ conv_w,   // [D]
    const float* __restrict__ conv_bp,  // [1]
    float* __restrict__ conv_out,       // [B*S, D]
    float* __restrict__ conv_wts_out)   // [B*S, P]
{
    __shared__ float tile[PP * DD];   // 64 KiB
    __shared__ float scores[PP];
    __shared__ float wts[PP];

    const int bs   = blockIdx.x;      // 0..4095
    const int t    = threadIdx.x;     // 0..255
    const int lane = t & 63;
    const int wv   = t >> 6;

    const float4* src = reinterpret_cast<const float4*>(inp + (size_t)bs * (PP * DD));
    const float4  cw  = reinterpret_cast<const float4*>(conv_w)[lane];
    const float   cb  = conv_bp[0];

    // 16 outstanding float4 loads per thread (coalesced, flat tile copy)
    float4 v[16];
#pragma unroll
    for (int i = 0; i < 16; ++i) v[i] = src[i * 256 + t];

    float part[16];
#pragma unroll
    for (int i = 0; i < 16; ++i) {
        reinterpret_cast<float4*>(&tile[(i * 256 + t) * 4])[0] = v[i];
        part[i] = v[i].x * cw.x + v[i].y * cw.y + v[i].z * cw.z + v[i].w * cw.w;
    }
    // Each wave wv owns rows p = 4*i + wv; reduce over 64 lanes (d4 = lane).
#pragma unroll
    for (int i = 0; i < 16; ++i) {
#pragma unroll
        for (int m = 32; m >= 1; m >>= 1) part[i] += __shfl_xor(part[i], m);
        if (lane == i) scores[i * 4 + wv] = part[i] + cb;  // compile-time reg idx
    }
    __syncthreads();

    // softmax over P=64, wave 0
    if (wv == 0) {
        float s = scores[lane];
        float mx = s;
#pragma unroll
        for (int m = 32; m >= 1; m >>= 1) mx = fmaxf(mx, __shfl_xor(mx, m));
        float e = __expf(s - mx);
        float sm = e;
#pragma unroll
        for (int m = 32; m >= 1; m >>= 1) sm += __shfl_xor(sm, m);
        float w = e / sm;
        wts[lane] = w;
        conv_wts_out[(size_t)bs * PP + lane] = w;
    }
    __syncthreads();

    // weighted sum over p: thread t = output dim d
    float acc = 0.f;
#pragma unroll 8
    for (int p = 0; p < PP; ++p) acc += wts[p] * tile[p * DD + t];
    conv_out[(size_t)bs * DD + t] = acc;
}

// ---------------------------------------------------------------------------
// Kernel 2: xg GEMM. C[4096,768] = A[4096,256] @ W'[768,256]^T + b_ih.
// cols 0..383 = forward gates, 384..767 = backward gates.
// fp32 vector GEMM: 128x128 tile, BK=32, transposed LDS ([BK][132]), 8x8 uT.
// ---------------------------------------------------------------------------
#define GBM 128
#define GBN 128
#define GBK 32
#define GAS 132   // LDS row stride (floats) for [GBK][GAS] transposed tiles

__global__ __launch_bounds__(256) void k_xg(
    const float* __restrict__ A,    // [4096,256]
    const float* __restrict__ Wf,   // [384,256]
    const float* __restrict__ Wb,   // [384,256]
    const float* __restrict__ bf,   // [384]
    const float* __restrict__ bb,   // [384]
    float* __restrict__ xg)         // [4096,768]
{
    __shared__ float as_[GBK * GAS];
    __shared__ float bs_[GBK * GAS];

    const int t  = threadIdx.x;
    const int i0 = blockIdx.x * GBM;       // 0..3968
    const int j0 = blockIdx.y * GBN;       // 0,128,...,640
    const int tx = t & 15, ty = t >> 4;

    const float* Wsrc = (j0 < 384) ? (Wf + (size_t)j0 * DD) : (Wb + (size_t)(j0 - 384) * DD);
    const float* bsrc = (j0 < 384) ? (bf + j0) : (bb + (j0 - 384));

    float acc[8][8];
#pragma unroll
    for (int ii = 0; ii < 8; ++ii)
#pragma unroll
        for (int jj = 0; jj < 8; ++jj) acc[ii][jj] = 0.f;

    for (int kt = 0; kt < DD; kt += GBK) {
        __syncthreads();
#pragma unroll
        for (int p = 0; p < 4; ++p) {
            const int idx = p * 256 + t;   // 0..1023
            const int r   = idx >> 3;      // 0..127
            const int k4  = idx & 7;       // 0..7
            const float4 av = *reinterpret_cast<const float4*>(&A[(size_t)(i0 + r) * DD + kt + k4 * 4]);
            const float4 bv = *reinterpret_cast<const float4*>(&Wsrc[(size_t)r * DD + kt + k4 * 4]);
            as_[(k4 * 4 + 0) * GAS + r] = av.x;
            as_[(k4 * 4 + 1) * GAS + r] = av.y;
            as_[(k4 * 4 + 2) * GAS + r] = av.z;
            as_[(k4 * 4 + 3) * GAS + r] = av.w;
            bs_[(k4 * 4 + 0) * GAS + r] = bv.x;
            bs_[(k4 * 4 + 1) * GAS + r] = bv.y;
            bs_[(k4 * 4 + 2) * GAS + r] = bv.z;
            bs_[(k4 * 4 + 3) * GAS + r] = bv.w;
        }
        __syncthreads();
#pragma unroll 8
        for (int k = 0; k < GBK; ++k) {
            float a[8], bq[8];
            *reinterpret_cast<float4*>(&a[0])  = *reinterpret_cast<const float4*>(&as_[k * GAS + ty * 8]);
            *reinterpret_cast<float4*>(&a[4])  = *reinterpret_cast<const float4*>(&as_[k * GAS + ty * 8 + 4]);
            *reinterpret_cast<float4*>(&bq[0]) = *reinterpret_cast<const float4*>(&bs_[k * GAS + tx * 8]);
            *reinterpret_cast<float4*>(&bq[4]) = *reinterpret_cast<const float4*>(&bs_[k * GAS + tx * 8 + 4]);
#pragma unroll
            for (int ii = 0; ii < 8; ++ii)
#pragma unroll
                for (int jj = 0; jj < 8; ++jj) acc[ii][jj] += a[ii] * bq[jj];
        }
    }

    float bias[8];
#pragma unroll
    for (int jj = 0; jj < 8; ++jj) bias[jj] = bsrc[tx * 8 + jj];
#pragma unroll
    for (int ii = 0; ii < 8; ++ii) {
        float* dst = &xg[(size_t)(i0 + ty * 8 + ii) * 768 + j0 + tx * 8];
        float4 o0, o1;
        o0.x = acc[ii][0] + bias[0]; o0.y = acc[ii][1] + bias[1];
        o0.z = acc[ii][2] + bias[2]; o0.w = acc[ii][3] + bias[3];
        o1.x = acc[ii][4] + bias[4]; o1.y = acc[ii][5] + bias[5];
        o1.z = acc[ii][6] + bias[6]; o1.w = acc[ii][7] + bias[7];
        reinterpret_cast<float4*>(dst)[0] = o0;
        reinterpret_cast<float4*>(dst + 4)[0] = o1;
    }
}

// ---------------------------------------------------------------------------
// Kernel 3: bidirectional GRU recurrence. One block per (b, dir): 64 blocks,
// 384 threads. Thread g holds W_hh row g (128 fp32) in VGPRs. h in LDS.
// ---------------------------------------------------------------------------
__device__ __forceinline__ float sigm(float x) { return 1.f / (1.f + __expf(-x)); }
__device__ __forceinline__ float tanh_f(float x) { return 2.f / (1.f + __expf(-2.f * x)) - 1.f; }

__global__ __launch_bounds__(384) void k_gru(
    const float* __restrict__ xg,    // [4096, 768]
    const float* __restrict__ Whf,   // [384,128]
    const float* __restrict__ Whb,   // [384,128]
    const float* __restrict__ bhf,   // [384]
    const float* __restrict__ bhb,   // [384]
    float* __restrict__ states)      // [4096, 256] (= d_out states_rnn)
{
    const int blk = blockIdx.x;   // 0..63
    const int b   = blk >> 1;
    const int dir = blk & 1;
    const int g   = threadIdx.x;  // 0..383

    __shared__ float hbuf[HH];
    __shared__ float hg[3 * HH];

    const float* Wh  = dir ? Whb : Whf;
    const float  bhh = (dir ? bhb : bhf)[g];

    float4 w[32];
    const float4* wrow = reinterpret_cast<const float4*>(Wh + (size_t)g * HH);
#pragma unroll
    for (int k = 0; k < 32; ++k) w[k] = wrow[k];

    if (g < HH) hbuf[g] = 0.f;
    __syncthreads();

    const float* xg_b = xg + (size_t)b * SS * 768 + dir * 384;

    for (int step = 0; step < SS; ++step) {
        const int s = dir ? (SS - 1 - step) : step;
        // phase A: hg = W_hh @ h + b_hh  (uniform LDS broadcast reads)
        float acc = bhh;
#pragma unroll
        for (int k = 0; k < 32; ++k) {
            const float4 h4 = *reinterpret_cast<const float4*>(&hbuf[k * 4]);
            acc += w[k].x * h4.x + w[k].y * h4.y + w[k].z * h4.z + w[k].w * h4.w;
        }
        hg[g] = acc;
        __syncthreads();
        // phase B: gates + state update (threads 0..127)
        if (g < HH) {
            const float* xr = xg_b + (size_t)s * 768;
            const float xrv = xr[g], xzv = xr[HH + g], xnv = xr[2 * HH + g];
            const float hr = hg[g], hz = hg[HH + g], hn = hg[2 * HH + g];
            const float hp = hbuf[g];
            const float r = sigm(xrv + hr);
            const float z = sigm(xzv + hz);
            const float n = tanh_f(xnv + r * hn);
            const float hnew = (1.f - z) * n + z * hp;
            hbuf[g] = hnew;
            states[((size_t)b * SS + s) * 256 + dir * HH + g] = hnew;
        }
        __syncthreads();
    }
}

// ---------------------------------------------------------------------------
// Kernel 4: time attention (conv2 + softmax over S) + context + linear+softmax.
// One block per batch item.
// ---------------------------------------------------------------------------
__global__ __launch_bounds__(256) void k_attn2(
    const float* __restrict__ states,   // [B*S, 256]
    const float* __restrict__ c2w,      // [3, 256]
    const float* __restrict__ c2b,      // [3]
    const float* __restrict__ demoip,   // [B, 3]
    const float* __restrict__ lin_w,    // [2, 771]
    const float* __restrict__ lin_b,    // [2]
    float* __restrict__ out,            // [B, 2]
    float* __restrict__ alpha_out,      // [B, 3, 128]
    float* __restrict__ ctx_out)        // [B, 768]
{
    const int b    = blockIdx.x;
    const int t    = threadIdx.x;
    const int lane = t & 63;
    const int wv   = t >> 6;

    __shared__ float sc[NF * SS];
    __shared__ float al[NF * SS];
    __shared__ float ctx[768];
    __shared__ float lo[2];

    const float* st = states + (size_t)b * SS * 256;

    // phase 1: alpha_scores[f][s]
    for (int o = t; o < NF * SS; o += 256) {
        const int f = o >> 7, s = o & 127;
        const float* row  = st + (size_t)s * 256;
        const float* wrow = c2w + f * 256;
        float a = 0.f;
#pragma unroll 8
        for (int h = 0; h < 256; ++h) a += row[h] * wrow[h];
        sc[o] = a + c2b[f];
    }
    __syncthreads();

    // phase 2: softmax over s per filter (waves 0..2)
    if (wv < NF) {
        const float v0 = sc[wv * SS + lane], v1 = sc[wv * SS + 64 + lane];
        float mx = fmaxf(v0, v1);
#pragma unroll
        for (int m = 32; m >= 1; m >>= 1) mx = fmaxf(mx, __shfl_xor(mx, m));
        const float e0 = __expf(v0 - mx), e1 = __expf(v1 - mx);
        float sm = e0 + e1;
#pragma unroll
        for (int m = 32; m >= 1; m >>= 1) sm += __shfl_xor(sm, m);
        const float r = 1.f / sm;
        al[wv * SS + lane]      = e0 * r;
        al[wv * SS + 64 + lane] = e1 * r;
        alpha_out[((size_t)b * NF + wv) * SS + lane]      = e0 * r;
        alpha_out[((size_t)b * NF + wv) * SS + 64 + lane] = e1 * r;
    }
    __syncthreads();

    // phase 3: context[f][h], thread t = h
    float c0 = 0.f, c1 = 0.f, c2 = 0.f;
#pragma unroll 4
    for (int s = 0; s < SS; ++s) {
        const float sv = st[(size_t)s * 256 + t];
        c0 += al[s] * sv;
        c1 += al[SS + s] * sv;
        c2 += al[2 * SS + s] * sv;
    }
    ctx[t]       = c0;
    ctx[256 + t] = c1;
    ctx[512 + t] = c2;
    ctx_out[(size_t)b * 768 + t]       = c0;
    ctx_out[(size_t)b * 768 + 256 + t] = c1;
    ctx_out[(size_t)b * 768 + 512 + t] = c2;
    __syncthreads();

    // phase 4: final linear (771 -> 2) + softmax
    if (t < 2) {
        float a = lin_b[t];
        const float* lw = lin_w + (size_t)t * 771;
#pragma unroll 8
        for (int i = 0; i < 768; ++i) a += ctx[i] * lw[i];
        for (int k = 0; k < 3; ++k) a += demoip[b * 3 + k] * lw[768 + k];
        lo[t] = a;
    }
    __syncthreads();
    if (t == 0) {
        const float m  = fmaxf(lo[0], lo[1]);
        const float e0 = __expf(lo[0] - m), e1 = __expf(lo[1] - m);
        const float s  = e0 + e1;
        out[b * 2 + 0] = e0 / s;
        out[b * 2 + 1] = e1 / s;
    }
}

// ---------------------------------------------------------------------------
extern "C" void kernel_launch(void* const* d_in, const int* in_sizes, int n_in,
                              void* d_out, int out_size, void* d_ws, size_t ws_size,
                              hipStream_t stream) {
    const float* inp     = (const float*)d_in[0];
    const float* demoip  = (const float*)d_in[1];
    const float* conv_w  = (const float*)d_in[2];
    const float* conv_b  = (const float*)d_in[3];
    const float* c2w     = (const float*)d_in[4];
    const float* c2b     = (const float*)d_in[5];
    const float* Wih_f   = (const float*)d_in[6];
    const float* Whh_f   = (const float*)d_in[7];
    const float* bih_f   = (const float*)d_in[8];
    const float* bhh_f   = (const float*)d_in[9];
    const float* Wih_b   = (const float*)d_in[10];
    const float* Whh_b   = (const float*)d_in[11];
    const float* bih_b   = (const float*)d_in[12];
    const float* bhh_b   = (const float*)d_in[13];
    const float* lin_w   = (const float*)d_in[14];
    const float* lin_b   = (const float*)d_in[15];

    // d_out layout: out[64] | alpha[12288] | states[1048576] | context[24576] | conv_wts[262144]
    float* out      = (float*)d_out;
    float* alpha    = out + 64;
    float* states   = out + 12352;
    float* context  = out + 1060928;
    float* conv_wts = out + 1085504;

    // workspace: conv_out [4096*256] | xg [4096*768]  (16 MiB total)
    float* conv_out = (float*)d_ws;
    float* xg       = conv_out + (size_t)4096 * 256;

    k_pool<<<dim3(BB * SS), dim3(256), 0, stream>>>(inp, conv_w, conv_b, conv_out, conv_wts);
    k_xg<<<dim3(4096 / GBM, 768 / GBN), dim3(256), 0, stream>>>(conv_out, Wih_f, Wih_b, bih_f, bih_b, xg);
    k_gru<<<dim3(64), dim3(384), 0, stream>>>(xg, Whh_f, Whh_b, bhh_f, bhh_b, states);
    k_attn2<<<dim3(BB), dim3(256), 0, stream>>>(states, c2w, c2b, demoip, lin_w, lin_b, out, alpha, context);
}

// Round 2
// 285.245 us; speedup vs baseline: 1.0998x; 1.0998x over previous
//
#include <hip/hip_runtime.h>
#include <hip/hip_bf16.h>

// Problem dims (compile-time constants from the reference)
#define BB 32
#define SS 128
#define PP 64
#define DD 256
#define HH 128
#define NF 3

// ---------------------------------------------------------------------------
// Kernel 1: conv-attention pooling over the pad dim.
// One block per (b,s). Stage [64][256] fp32 tile in LDS (64 KiB) so HBM is
// read exactly once. scores -> softmax(P) -> weighted sum over P.
// ---------------------------------------------------------------------------
__global__ __launch_bounds__(256) void k_pool(
    const float* __restrict__ inp,      // [B,S,P,D]
    const float* __restrict__ conv_w,   // [D]
    const float* __restrict__ conv_bp,  // [1]
    float* __restrict__ conv_out,       // [B*S, D]
    float* __restrict__ conv_wts_out)   // [B*S, P]
{
    __shared__ float tile[PP * DD];   // 64 KiB
    __shared__ float scores[PP];
    __shared__ float wts[PP];

    const int bs   = blockIdx.x;      // 0..4095
    const int t    = threadIdx.x;     // 0..255
    const int lane = t & 63;
    const int wv   = t >> 6;

    const float4* src = reinterpret_cast<const float4*>(inp + (size_t)bs * (PP * DD));
    const float4  cw  = reinterpret_cast<const float4*>(conv_w)[lane];
    const float   cb  = conv_bp[0];

    // 16 outstanding float4 loads per thread (coalesced, flat tile copy)
    float4 v[16];
#pragma unroll
    for (int i = 0; i < 16; ++i) v[i] = src[i * 256 + t];

    float part[16];
#pragma unroll
    for (int i = 0; i < 16; ++i) {
        reinterpret_cast<float4*>(&tile[(i * 256 + t) * 4])[0] = v[i];
        part[i] = v[i].x * cw.x + v[i].y * cw.y + v[i].z * cw.z + v[i].w * cw.w;
    }
    // Each wave wv owns rows p = 4*i + wv; reduce over 64 lanes (d4 = lane).
#pragma unroll
    for (int i = 0; i < 16; ++i) {
#pragma unroll
        for (int m = 32; m >= 1; m >>= 1) part[i] += __shfl_xor(part[i], m);
        if (lane == i) scores[i * 4 + wv] = part[i] + cb;  // compile-time reg idx
    }
    __syncthreads();

    // softmax over P=64, wave 0
    if (wv == 0) {
        float s = scores[lane];
        float mx = s;
#pragma unroll
        for (int m = 32; m >= 1; m >>= 1) mx = fmaxf(mx, __shfl_xor(mx, m));
        float e = __expf(s - mx);
        float sm = e;
#pragma unroll
        for (int m = 32; m >= 1; m >>= 1) sm += __shfl_xor(sm, m);
        float w = e / sm;
        wts[lane] = w;
        conv_wts_out[(size_t)bs * PP + lane] = w;
    }
    __syncthreads();

    // weighted sum over p: thread t = output dim d
    float acc = 0.f;
#pragma unroll 8
    for (int p = 0; p < PP; ++p) acc += wts[p] * tile[p * DD + t];
    conv_out[(size_t)bs * DD + t] = acc;
}

// ---------------------------------------------------------------------------
// Kernel 2: xg GEMM. C[4096,768] = A[4096,256] @ W'[768,256]^T + b_ih.
// cols 0..383 = forward gates, 384..767 = backward gates.
// fp32 vector GEMM: 128x128 tile, BK=32, transposed LDS ([BK][132]), 8x8 uT.
// ---------------------------------------------------------------------------
#define GBM 128
#define GBN 128
#define GBK 32
#define GAS 132   // LDS row stride (floats) for [GBK][GAS] transposed tiles

__global__ __launch_bounds__(256) void k_xg(
    const float* __restrict__ A,    // [4096,256]
    const float* __restrict__ Wf,   // [384,256]
    const float* __restrict__ Wb,   // [384,256]
    const float* __restrict__ bf,   // [384]
    const float* __restrict__ bb,   // [384]
    float* __restrict__ xg)         // [4096,768]
{
    __shared__ float as_[GBK * GAS];
    __shared__ float bs_[GBK * GAS];

    const int t  = threadIdx.x;
    const int i0 = blockIdx.x * GBM;       // 0..3968
    const int j0 = blockIdx.y * GBN;       // 0,128,...,640
    const int tx = t & 15, ty = t >> 4;

    const float* Wsrc = (j0 < 384) ? (Wf + (size_t)j0 * DD) : (Wb + (size_t)(j0 - 384) * DD);
    const float* bsrc = (j0 < 384) ? (bf + j0) : (bb + (j0 - 384));

    float acc[8][8];
#pragma unroll
    for (int ii = 0; ii < 8; ++ii)
#pragma unroll
        for (int jj = 0; jj < 8; ++jj) acc[ii][jj] = 0.f;

    for (int kt = 0; kt < DD; kt += GBK) {
        __syncthreads();
#pragma unroll
        for (int p = 0; p < 4; ++p) {
            const int idx = p * 256 + t;   // 0..1023
            const int r   = idx >> 3;      // 0..127
            const int k4  = idx & 7;       // 0..7
            const float4 av = *reinterpret_cast<const float4*>(&A[(size_t)(i0 + r) * DD + kt + k4 * 4]);
            const float4 bv = *reinterpret_cast<const float4*>(&Wsrc[(size_t)r * DD + kt + k4 * 4]);
            as_[(k4 * 4 + 0) * GAS + r] = av.x;
            as_[(k4 * 4 + 1) * GAS + r] = av.y;
            as_[(k4 * 4 + 2) * GAS + r] = av.z;
            as_[(k4 * 4 + 3) * GAS + r] = av.w;
            bs_[(k4 * 4 + 0) * GAS + r] = bv.x;
            bs_[(k4 * 4 + 1) * GAS + r] = bv.y;
            bs_[(k4 * 4 + 2) * GAS + r] = bv.z;
            bs_[(k4 * 4 + 3) * GAS + r] = bv.w;
        }
        __syncthreads();
#pragma unroll 8
        for (int k = 0; k < GBK; ++k) {
            float a[8], bq[8];
            *reinterpret_cast<float4*>(&a[0])  = *reinterpret_cast<const float4*>(&as_[k * GAS + ty * 8]);
            *reinterpret_cast<float4*>(&a[4])  = *reinterpret_cast<const float4*>(&as_[k * GAS + ty * 8 + 4]);
            *reinterpret_cast<float4*>(&bq[0]) = *reinterpret_cast<const float4*>(&bs_[k * GAS + tx * 8]);
            *reinterpret_cast<float4*>(&bq[4]) = *reinterpret_cast<const float4*>(&bs_[k * GAS + tx * 8 + 4]);
#pragma unroll
            for (int ii = 0; ii < 8; ++ii)
#pragma unroll
                for (int jj = 0; jj < 8; ++jj) acc[ii][jj] += a[ii] * bq[jj];
        }
    }

    float bias[8];
#pragma unroll
    for (int jj = 0; jj < 8; ++jj) bias[jj] = bsrc[tx * 8 + jj];
#pragma unroll
    for (int ii = 0; ii < 8; ++ii) {
        float* dst = &xg[(size_t)(i0 + ty * 8 + ii) * 768 + j0 + tx * 8];
        float4 o0, o1;
        o0.x = acc[ii][0] + bias[0]; o0.y = acc[ii][1] + bias[1];
        o0.z = acc[ii][2] + bias[2]; o0.w = acc[ii][3] + bias[3];
        o1.x = acc[ii][4] + bias[4]; o1.y = acc[ii][5] + bias[5];
        o1.z = acc[ii][6] + bias[6]; o1.w = acc[ii][7] + bias[7];
        reinterpret_cast<float4*>(dst)[0] = o0;
        reinterpret_cast<float4*>(dst + 4)[0] = o1;
    }
}

// ---------------------------------------------------------------------------
// Kernel 3: bidirectional GRU recurrence. One block per (b, dir): 64 blocks,
// 768 threads (12 waves). Thread t = (row g = t>>1, half = t&1): 64 MACs over
// one half of h, 4 independent fmaf chains, __shfl_xor(1) pair-reduce.
// xg rows for step s+1 are prefetched into registers during phase A of step s.
// ---------------------------------------------------------------------------
__device__ __forceinline__ float sigm(float x) { return 1.f / (1.f + __expf(-x)); }
__device__ __forceinline__ float tanh_f(float x) { return 2.f / (1.f + __expf(-2.f * x)) - 1.f; }

__global__ __launch_bounds__(768) void k_gru(
    const float* __restrict__ xg,    // [4096, 768]
    const float* __restrict__ Whf,   // [384,128]
    const float* __restrict__ Whb,   // [384,128]
    const float* __restrict__ bhf,   // [384]
    const float* __restrict__ bhb,   // [384]
    float* __restrict__ states)      // [4096, 256] (= d_out states_rnn)
{
    const int blk  = blockIdx.x;   // 0..63
    const int b    = blk >> 1;
    const int dir  = blk & 1;
    const int t    = threadIdx.x;  // 0..767
    const int g    = t >> 1;       // row 0..383
    const int half = t & 1;

    __shared__ float hbuf[HH];
    __shared__ float hg[3 * HH];

    const float* Wh  = dir ? Whb : Whf;
    const float  bhh = (dir ? bhb : bhf)[g];

    // 64 weights per thread (16 float4 = 64 VGPRs)
    float4 w[16];
    const float4* wrow = reinterpret_cast<const float4*>(Wh + (size_t)g * HH + half * 64);
#pragma unroll
    for (int k = 0; k < 16; ++k) w[k] = wrow[k];

    if (t < HH) hbuf[t] = 0.f;
    __syncthreads();

    const float* xg_b = xg + (size_t)b * SS * 768 + dir * 384;

    // preload xg row for step 0
    float xrv = 0.f, xzv = 0.f, xnv = 0.f;
    float xrn = 0.f, xzn = 0.f, xnn = 0.f;
    {
        const int s0 = dir ? (SS - 1) : 0;
        if (t < HH) {
            const float* xr = xg_b + (size_t)s0 * 768;
            xrv = xr[t]; xzv = xr[HH + t]; xnv = xr[2 * HH + t];
        }
    }

    for (int step = 0; step < SS; ++step) {
        const int s = dir ? (SS - 1 - step) : step;

        // --- phase A: prefetch next xg row (hidden under matvec+barrier) ---
        if (t < HH && step + 1 < SS) {
            const int sn = dir ? (SS - 2 - step) : (step + 1);
            const float* xr = xg_b + (size_t)sn * 768;
            xrn = xr[t]; xzn = xr[HH + t]; xnn = xr[2 * HH + t];
        }

        // --- matvec: hg = W_hh @ h + b_hh, 64 MACs/thread, 4 acc chains ---
        const float4* hsrc = reinterpret_cast<const float4*>(&hbuf[half * 64]);
        float a0 = 0.f, a1 = 0.f, a2 = 0.f, a3 = 0.f;
#pragma unroll
        for (int k = 0; k < 16; k += 4) {
            const float4 h0 = hsrc[k + 0];
            const float4 h1 = hsrc[k + 1];
            const float4 h2 = hsrc[k + 2];
            const float4 h3 = hsrc[k + 3];
            a0 = fmaf(w[k + 0].x, h0.x, a0); a0 = fmaf(w[k + 0].y, h0.y, a0);
            a0 = fmaf(w[k + 0].z, h0.z, a0); a0 = fmaf(w[k + 0].w, h0.w, a0);
            a1 = fmaf(w[k + 1].x, h1.x, a1); a1 = fmaf(w[k + 1].y, h1.y, a1);
            a1 = fmaf(w[k + 1].z, h1.z, a1); a1 = fmaf(w[k + 1].w, h1.w, a1);
            a2 = fmaf(w[k + 2].x, h2.x, a2); a2 = fmaf(w[k + 2].y, h2.y, a2);
            a2 = fmaf(w[k + 2].z, h2.z, a2); a2 = fmaf(w[k + 2].w, h2.w, a2);
            a3 = fmaf(w[k + 3].x, h3.x, a3); a3 = fmaf(w[k + 3].y, h3.y, a3);
            a3 = fmaf(w[k + 3].z, h3.z, a3); a3 = fmaf(w[k + 3].w, h3.w, a3);
        }
        float part = (a0 + a1) + (a2 + a3);
        part += __shfl_xor(part, 1);          // combine the two halves (adjacent lanes)
        if (half == 0) hg[g] = part + bhh;
        __syncthreads();

        // --- phase B: gates + state update (threads 0..127) ---
        if (t < HH) {
            const float hp = hbuf[t];
            const float r  = sigm(xrv + hg[t]);
            const float z  = sigm(xzv + hg[HH + t]);
            const float n  = tanh_f(xnv + r * hg[2 * HH + t]);
            const float hnew = (1.f - z) * n + z * hp;
            hbuf[t] = hnew;
            states[((size_t)b * SS + s) * 256 + dir * HH + t] = hnew;
            xrv = xrn; xzv = xzn; xnv = xnn;   // rotate prefetched row in
        }
        __syncthreads();
    }
}

// ---------------------------------------------------------------------------
// Kernel 4: time attention (conv2 + softmax over S) + context + linear+softmax.
// One block per batch item.
// ---------------------------------------------------------------------------
__global__ __launch_bounds__(256) void k_attn2(
    const float* __restrict__ states,   // [B*S, 256]
    const float* __restrict__ c2w,      // [3, 256]
    const float* __restrict__ c2b,      // [3]
    const float* __restrict__ demoip,   // [B, 3]
    const float* __restrict__ lin_w,    // [2, 771]
    const float* __restrict__ lin_b,    // [2]
    float* __restrict__ out,            // [B, 2]
    float* __restrict__ alpha_out,      // [B, 3, 128]
    float* __restrict__ ctx_out)        // [B, 768]
{
    const int b    = blockIdx.x;
    const int t    = threadIdx.x;
    const int lane = t & 63;
    const int wv   = t >> 6;

    __shared__ float sc[NF * SS];
    __shared__ float al[NF * SS];
    __shared__ float ctx[768];
    __shared__ float lo[2];

    const float* st = states + (size_t)b * SS * 256;

    // phase 1: alpha_scores[f][s]
    for (int o = t; o < NF * SS; o += 256) {
        const int f = o >> 7, s = o & 127;
        const float* row  = st + (size_t)s * 256;
        const float* wrow = c2w + f * 256;
        float a = 0.f;
#pragma unroll 8
        for (int h = 0; h < 256; ++h) a += row[h] * wrow[h];
        sc[o] = a + c2b[f];
    }
    __syncthreads();

    // phase 2: softmax over s per filter (waves 0..2)
    if (wv < NF) {
        const float v0 = sc[wv * SS + lane], v1 = sc[wv * SS + 64 + lane];
        float mx = fmaxf(v0, v1);
#pragma unroll
        for (int m = 32; m >= 1; m >>= 1) mx = fmaxf(mx, __shfl_xor(mx, m));
        const float e0 = __expf(v0 - mx), e1 = __expf(v1 - mx);
        float sm = e0 + e1;
#pragma unroll
        for (int m = 32; m >= 1; m >>= 1) sm += __shfl_xor(sm, m);
        const float r = 1.f / sm;
        al[wv * SS + lane]      = e0 * r;
        al[wv * SS + 64 + lane] = e1 * r;
        alpha_out[((size_t)b * NF + wv) * SS + lane]      = e0 * r;
        alpha_out[((size_t)b * NF + wv) * SS + 64 + lane] = e1 * r;
    }
    __syncthreads();

    // phase 3: context[f][h], thread t = h
    float c0 = 0.f, c1 = 0.f, c2 = 0.f;
#pragma unroll 4
    for (int s = 0; s < SS; ++s) {
        const float sv = st[(size_t)s * 256 + t];
        c0 += al[s] * sv;
        c1 += al[SS + s] * sv;
        c2 += al[2 * SS + s] * sv;
    }
    ctx[t]       = c0;
    ctx[256 + t] = c1;
    ctx[512 + t] = c2;
    ctx_out[(size_t)b * 768 + t]       = c0;
    ctx_out[(size_t)b * 768 + 256 + t] = c1;
    ctx_out[(size_t)b * 768 + 512 + t] = c2;
    __syncthreads();

    // phase 4: final linear (771 -> 2) + softmax
    if (t < 2) {
        float a = lin_b[t];
        const float* lw = lin_w + (size_t)t * 771;
#pragma unroll 8
        for (int i = 0; i < 768; ++i) a += ctx[i] * lw[i];
        for (int k = 0; k < 3; ++k) a += demoip[b * 3 + k] * lw[768 + k];
        lo[t] = a;
    }
    __syncthreads();
    if (t == 0) {
        const float m  = fmaxf(lo[0], lo[1]);
        const float e0 = __expf(lo[0] - m), e1 = __expf(lo[1] - m);
        const float s  = e0 + e1;
        out[b * 2 + 0] = e0 / s;
        out[b * 2 + 1] = e1 / s;
    }
}

// ---------------------------------------------------------------------------
extern "C" void kernel_launch(void* const* d_in, const int* in_sizes, int n_in,
                              void* d_out, int out_size, void* d_ws, size_t ws_size,
                              hipStream_t stream) {
    const float* inp     = (const float*)d_in[0];
    const float* demoip  = (const float*)d_in[1];
    const float* conv_w  = (const float*)d_in[2];
    const float* conv_b  = (const float*)d_in[3];
    const float* c2w     = (const float*)d_in[4];
    const float* c2b     = (const float*)d_in[5];
    const float* Wih_f   = (const float*)d_in[6];
    const float* Whh_f   = (const float*)d_in[7];
    const float* bih_f   = (const float*)d_in[8];
    const float* bhh_f   = (const float*)d_in[9];
    const float* Wih_b   = (const float*)d_in[10];
    const float* Whh_b   = (const float*)d_in[11];
    const float* bih_b   = (const float*)d_in[12];
    const float* bhh_b   = (const float*)d_in[13];
    const float* lin_w   = (const float*)d_in[14];
    const float* lin_b   = (const float*)d_in[15];

    // d_out layout: out[64] | alpha[12288] | states[1048576] | context[24576] | conv_wts[262144]
    float* out      = (float*)d_out;
    float* alpha    = out + 64;
    float* states   = out + 12352;
    float* context  = out + 1060928;
    float* conv_wts = out + 1085504;

    // workspace: conv_out [4096*256] | xg [4096*768]  (16 MiB total)
    float* conv_out = (float*)d_ws;
    float* xg       = conv_out + (size_t)4096 * 256;

    k_pool<<<dim3(BB * SS), dim3(256), 0, stream>>>(inp, conv_w, conv_b, conv_out, conv_wts);
    k_xg<<<dim3(4096 / GBM, 768 / GBN), dim3(256), 0, stream>>>(conv_out, Wih_f, Wih_b, bih_f, bih_b, xg);
    k_gru<<<dim3(64), dim3(768), 0, stream>>>(xg, Whh_f, Whh_b, bhh_f, bhh_b, states);
    k_attn2<<<dim3(BB), dim3(256), 0, stream>>>(states, c2w, c2b, demoip, lin_w, lin_b, out, alpha, context);
}

// Round 3
// 229.290 us; speedup vs baseline: 1.3682x; 1.2440x over previous
//
#include <hip/hip_runtime.h>
#include <hip/hip_bf16.h>

// Problem dims (compile-time constants from the reference)
#define BB 32
#define SS 128
#define PP 64
#define DD 256
#define HH 128
#define NF 3

// ---------------------------------------------------------------------------
// Kernel 1: conv-attention pooling over the pad dim.
// One block per (b,s). Rows held in REGISTERS (16 float4/thread); weighted
// sum reduced via a 4 KB LDS partial buffer (no 64 KiB tile -> 5+ blocks/CU).
// ---------------------------------------------------------------------------
__global__ __launch_bounds__(256) void k_pool(
    const float* __restrict__ inp,      // [B,S,P,D]
    const float* __restrict__ conv_w,   // [D]
    const float* __restrict__ conv_bp,  // [1]
    float* __restrict__ conv_out,       // [B*S, D]
    float* __restrict__ conv_wts_out)   // [B*S, P]
{
    __shared__ float scores[PP];
    __shared__ float wts[PP];
    __shared__ float4 part4[256];   // 4 KB

    const int bs   = blockIdx.x;      // 0..4095
    const int t    = threadIdx.x;     // 0..255
    const int lane = t & 63;
    const int wv   = t >> 6;

    const float4* src = reinterpret_cast<const float4*>(inp + (size_t)bs * (PP * DD));
    const float4  cw  = reinterpret_cast<const float4*>(conv_w)[lane];
    const float   cb  = conv_bp[0];

    // v[i] = row p = 4*i + wv, cols [lane*4, lane*4+4)
    float4 v[16];
#pragma unroll
    for (int i = 0; i < 16; ++i) v[i] = src[i * 256 + t];

    float part[16];
#pragma unroll
    for (int i = 0; i < 16; ++i)
        part[i] = v[i].x * cw.x + v[i].y * cw.y + v[i].z * cw.z + v[i].w * cw.w;

    // 64-lane butterfly per row; row p = 4*i + wv
#pragma unroll
    for (int i = 0; i < 16; ++i) {
#pragma unroll
        for (int m = 32; m >= 1; m >>= 1) part[i] += __shfl_xor(part[i], m);
        if (lane == i) scores[i * 4 + wv] = part[i] + cb;
    }
    __syncthreads();

    // softmax over P=64, wave 0
    if (wv == 0) {
        float s = scores[lane];
        float mx = s;
#pragma unroll
        for (int m = 32; m >= 1; m >>= 1) mx = fmaxf(mx, __shfl_xor(mx, m));
        float e = __expf(s - mx);
        float sm = e;
#pragma unroll
        for (int m = 32; m >= 1; m >>= 1) sm += __shfl_xor(sm, m);
        float w = e / sm;
        wts[lane] = w;
        conv_wts_out[(size_t)bs * PP + lane] = w;
    }
    __syncthreads();

    // weighted sum over the 16 register-held rows
    float4 acc = {0.f, 0.f, 0.f, 0.f};
#pragma unroll
    for (int i = 0; i < 16; ++i) {
        const float w = wts[4 * i + wv];
        acc.x = fmaf(w, v[i].x, acc.x);
        acc.y = fmaf(w, v[i].y, acc.y);
        acc.z = fmaf(w, v[i].z, acc.z);
        acc.w = fmaf(w, v[i].w, acc.w);
    }
    part4[t] = acc;
    __syncthreads();

    if (wv == 0) {
        float4 a = part4[lane];
        const float4 b1 = part4[64 + lane];
        const float4 b2 = part4[128 + lane];
        const float4 b3 = part4[192 + lane];
        a.x += b1.x + b2.x + b3.x;
        a.y += b1.y + b2.y + b3.y;
        a.z += b1.z + b2.z + b3.z;
        a.w += b1.w + b2.w + b3.w;
        reinterpret_cast<float4*>(conv_out + (size_t)bs * DD)[lane] = a;
    }
}

// ---------------------------------------------------------------------------
// Kernel 2: xg GEMM. C[4096,768] = A[4096,256] @ W'[768,256]^T + b_ih.
// 128x128 tile, BK=32, transposed LDS ([BK][132]), 8x8 uT, reg-prefetch
// staging (loads for tile kt+1 issued before compute of tile kt).
// ---------------------------------------------------------------------------
#define GBM 128
#define GBN 128
#define GBK 32
#define GAS 132   // LDS row stride (floats) for [GBK][GAS] transposed tiles

__global__ __launch_bounds__(256) void k_xg(
    const float* __restrict__ A,    // [4096,256]
    const float* __restrict__ Wf,   // [384,256]
    const float* __restrict__ Wb,   // [384,256]
    const float* __restrict__ bf,   // [384]
    const float* __restrict__ bb,   // [384]
    float* __restrict__ xg)         // [4096,768]
{
    __shared__ float as_[GBK * GAS];
    __shared__ float bs_[GBK * GAS];

    const int t  = threadIdx.x;
    const int i0 = blockIdx.x * GBM;
    const int j0 = blockIdx.y * GBN;
    const int tx = t & 15, ty = t >> 4;

    const float* Wsrc = (j0 < 384) ? (Wf + (size_t)j0 * DD) : (Wb + (size_t)(j0 - 384) * DD);
    const float* bsrc = (j0 < 384) ? (bf + j0) : (bb + (j0 - 384));

    float acc[8][8];
#pragma unroll
    for (int ii = 0; ii < 8; ++ii)
#pragma unroll
        for (int jj = 0; jj < 8; ++jj) acc[ii][jj] = 0.f;

    float4 pa[4], pb[4];
    // prefetch tile kt=0
#pragma unroll
    for (int p = 0; p < 4; ++p) {
        const int idx = p * 256 + t, r = idx >> 3, k4 = idx & 7;
        pa[p] = *reinterpret_cast<const float4*>(&A[(size_t)(i0 + r) * DD + k4 * 4]);
        pb[p] = *reinterpret_cast<const float4*>(&Wsrc[(size_t)r * DD + k4 * 4]);
    }

    for (int kt = 0; kt < DD; kt += GBK) {
        // write staged tile to LDS (transposed)
#pragma unroll
        for (int p = 0; p < 4; ++p) {
            const int idx = p * 256 + t, r = idx >> 3, k4 = idx & 7;
            as_[(k4 * 4 + 0) * GAS + r] = pa[p].x;
            as_[(k4 * 4 + 1) * GAS + r] = pa[p].y;
            as_[(k4 * 4 + 2) * GAS + r] = pa[p].z;
            as_[(k4 * 4 + 3) * GAS + r] = pa[p].w;
            bs_[(k4 * 4 + 0) * GAS + r] = pb[p].x;
            bs_[(k4 * 4 + 1) * GAS + r] = pb[p].y;
            bs_[(k4 * 4 + 2) * GAS + r] = pb[p].z;
            bs_[(k4 * 4 + 3) * GAS + r] = pb[p].w;
        }
        __syncthreads();
        // issue loads for next tile (hidden under compute)
        if (kt + GBK < DD) {
#pragma unroll
            for (int p = 0; p < 4; ++p) {
                const int idx = p * 256 + t, r = idx >> 3, k4 = idx & 7;
                pa[p] = *reinterpret_cast<const float4*>(&A[(size_t)(i0 + r) * DD + kt + GBK + k4 * 4]);
                pb[p] = *reinterpret_cast<const float4*>(&Wsrc[(size_t)r * DD + kt + GBK + k4 * 4]);
            }
        }
#pragma unroll 8
        for (int k = 0; k < GBK; ++k) {
            float a[8], bq[8];
            *reinterpret_cast<float4*>(&a[0])  = *reinterpret_cast<const float4*>(&as_[k * GAS + ty * 8]);
            *reinterpret_cast<float4*>(&a[4])  = *reinterpret_cast<const float4*>(&as_[k * GAS + ty * 8 + 4]);
            *reinterpret_cast<float4*>(&bq[0]) = *reinterpret_cast<const float4*>(&bs_[k * GAS + tx * 8]);
            *reinterpret_cast<float4*>(&bq[4]) = *reinterpret_cast<const float4*>(&bs_[k * GAS + tx * 8 + 4]);
#pragma unroll
            for (int ii = 0; ii < 8; ++ii)
#pragma unroll
                for (int jj = 0; jj < 8; ++jj) acc[ii][jj] += a[ii] * bq[jj];
        }
        __syncthreads();
    }

    float bias[8];
#pragma unroll
    for (int jj = 0; jj < 8; ++jj) bias[jj] = bsrc[tx * 8 + jj];
#pragma unroll
    for (int ii = 0; ii < 8; ++ii) {
        float* dst = &xg[(size_t)(i0 + ty * 8 + ii) * 768 + j0 + tx * 8];
        float4 o0, o1;
        o0.x = acc[ii][0] + bias[0]; o0.y = acc[ii][1] + bias[1];
        o0.z = acc[ii][2] + bias[2]; o0.w = acc[ii][3] + bias[3];
        o1.x = acc[ii][4] + bias[4]; o1.y = acc[ii][5] + bias[5];
        o1.z = acc[ii][6] + bias[6]; o1.w = acc[ii][7] + bias[7];
        reinterpret_cast<float4*>(dst)[0] = o0;
        reinterpret_cast<float4*>(dst + 4)[0] = o1;
    }
}

// ---------------------------------------------------------------------------
// Kernel 3: bidirectional GRU recurrence, v3.
// One block per (b,dir): 64 blocks x 512 threads (8 waves).
// Thread (t = tid>>2, q = tid&3) computes rows {t, 128+t, 256+t} over
// h-quarter [q*32, q*32+32): 96 FMA, 2x shfl_xor combine, gates in-register
// on q==0 lanes. ONE barrier/step, double-buffered h.
// xg staged in LDS in 16-step chunks, double-buffered, loads issued a full
// chunk (16 steps ~ 8000 cyc) ahead of their ds_write.
// ---------------------------------------------------------------------------
__device__ __forceinline__ float sigm(float x) { return 1.f / (1.f + __expf(-x)); }
__device__ __forceinline__ float tanh_f(float x) { return 2.f / (1.f + __expf(-2.f * x)) - 1.f; }

#define CH 16      // steps per xg chunk
#define XROW 384   // floats per step (3 gates x 128)

__global__ __launch_bounds__(512) void k_gru(
    const float* __restrict__ xg,    // [4096, 768]
    const float* __restrict__ Whf,   // [384,128]
    const float* __restrict__ Whb,   // [384,128]
    const float* __restrict__ bhf,   // [384]
    const float* __restrict__ bhb,   // [384]
    float* __restrict__ states)      // [4096, 256]
{
    const int blk = blockIdx.x;   // 0..63
    const int b   = blk >> 1;
    const int dir = blk & 1;
    const int tid = threadIdx.x;  // 0..511
    const int t   = tid >> 2;     // 0..127
    const int q   = tid & 3;      // h-quarter

    __shared__ float hb[2][HH];          // double-buffered hidden state
    __shared__ float xs[2][CH * XROW];   // 2 x 24 KB xg chunks

    const float* Wh = dir ? Whb : Whf;
    const float* bh = dir ? bhb : bhf;
    const float bhr = bh[t], bhz = bh[HH + t], bhn = bh[2 * HH + t];

    // weights: 3 rows x 32 cols = 96 floats in VGPRs
    float4 wr[8], wz[8], wn[8];
    {
        const float4* p0 = reinterpret_cast<const float4*>(Wh + (size_t)t * HH + q * 32);
        const float4* p1 = reinterpret_cast<const float4*>(Wh + (size_t)(HH + t) * HH + q * 32);
        const float4* p2 = reinterpret_cast<const float4*>(Wh + (size_t)(2 * HH + t) * HH + q * 32);
#pragma unroll
        for (int k = 0; k < 8; ++k) { wr[k] = p0[k]; wz[k] = p1[k]; wn[k] = p2[k]; }
    }

    const float* xg_bd = xg + (size_t)b * SS * 768 + dir * 384;

    float4 pf[3];
    // synchronous stage of chunk 0
#pragma unroll
    for (int j = 0; j < 3; ++j) {
        const int flat4 = j * 512 + tid;           // 0..1535
        const int sic = flat4 / 96, w4 = flat4 % 96;
        const int s = dir ? (SS - 1 - sic) : sic;
        pf[j] = *reinterpret_cast<const float4*>(xg_bd + (size_t)s * 768 + w4 * 4);
    }
#pragma unroll
    for (int j = 0; j < 3; ++j) {
        const int flat4 = j * 512 + tid;
        const int sic = flat4 / 96, w4 = flat4 % 96;
        *reinterpret_cast<float4*>(&xs[0][sic * XROW + w4 * 4]) = pf[j];
    }
    if (tid < HH) hb[0][tid] = 0.f;
    __syncthreads();
    // issue chunk 1 loads (consumed at step 15's boundary)
#pragma unroll
    for (int j = 0; j < 3; ++j) {
        const int flat4 = j * 512 + tid;
        const int sic = flat4 / 96, w4 = flat4 % 96;
        const int stp = CH + sic;
        const int s = dir ? (SS - 1 - stp) : stp;
        pf[j] = *reinterpret_cast<const float4*>(xg_bd + (size_t)s * 768 + w4 * 4);
    }

    for (int step = 0; step < SS; ++step) {
        const int s   = dir ? (SS - 1 - step) : step;
        const int cur = step & 1;
        const int sic = step & (CH - 1);
        const int buf = (step >> 4) & 1;

        const float* hrow = hb[cur];
        float4 hq[8];
#pragma unroll
        for (int k = 0; k < 8; ++k)
            hq[k] = *reinterpret_cast<const float4*>(&hrow[q * 32 + k * 4]);
        const float xrv = xs[buf][sic * XROW + t];
        const float xzv = xs[buf][sic * XROW + HH + t];
        const float xnv = xs[buf][sic * XROW + 2 * HH + t];
        const float hp  = hrow[t];

        // 96 FMA: 3 gates x 32 MACs, 2 chains each
        float ar0 = 0.f, ar1 = 0.f, az0 = 0.f, az1 = 0.f, an0 = 0.f, an1 = 0.f;
#pragma unroll
        for (int k = 0; k < 8; k += 2) {
            ar0 = fmaf(wr[k].x, hq[k].x, ar0); ar0 = fmaf(wr[k].y, hq[k].y, ar0);
            ar0 = fmaf(wr[k].z, hq[k].z, ar0); ar0 = fmaf(wr[k].w, hq[k].w, ar0);
            ar1 = fmaf(wr[k+1].x, hq[k+1].x, ar1); ar1 = fmaf(wr[k+1].y, hq[k+1].y, ar1);
            ar1 = fmaf(wr[k+1].z, hq[k+1].z, ar1); ar1 = fmaf(wr[k+1].w, hq[k+1].w, ar1);
            az0 = fmaf(wz[k].x, hq[k].x, az0); az0 = fmaf(wz[k].y, hq[k].y, az0);
            az0 = fmaf(wz[k].z, hq[k].z, az0); az0 = fmaf(wz[k].w, hq[k].w, az0);
            az1 = fmaf(wz[k+1].x, hq[k+1].x, az1); az1 = fmaf(wz[k+1].y, hq[k+1].y, az1);
            az1 = fmaf(wz[k+1].z, hq[k+1].z, az1); az1 = fmaf(wz[k+1].w, hq[k+1].w, az1);
            an0 = fmaf(wn[k].x, hq[k].x, an0); an0 = fmaf(wn[k].y, hq[k].y, an0);
            an0 = fmaf(wn[k].z, hq[k].z, an0); an0 = fmaf(wn[k].w, hq[k].w, an0);
            an1 = fmaf(wn[k+1].x, hq[k+1].x, an1); an1 = fmaf(wn[k+1].y, hq[k+1].y, an1);
            an1 = fmaf(wn[k+1].z, hq[k+1].z, an1); an1 = fmaf(wn[k+1].w, hq[k+1].w, an1);
        }
        float ar = ar0 + ar1, az = az0 + az1, an = an0 + an1;
        ar += __shfl_xor(ar, 1); ar += __shfl_xor(ar, 2);
        az += __shfl_xor(az, 1); az += __shfl_xor(az, 2);
        an += __shfl_xor(an, 1); an += __shfl_xor(an, 2);

        if (q == 0) {
            const float r = sigm(xrv + ar + bhr);
            const float z = sigm(xzv + az + bhz);
            const float n = tanh_f(xnv + r * (an + bhn));
            const float hnew = (1.f - z) * n + z * hp;
            hb[cur ^ 1][t] = hnew;
            states[((size_t)b * SS + s) * 256 + dir * HH + t] = hnew;
        }
        // chunk boundary: commit prefetched chunk to the other LDS buffer
        if (sic == CH - 1 && step != SS - 1) {
#pragma unroll
            for (int j = 0; j < 3; ++j) {
                const int flat4 = j * 512 + tid;
                const int sc = flat4 / 96, w4 = flat4 % 96;
                *reinterpret_cast<float4*>(&xs[buf ^ 1][sc * XROW + w4 * 4]) = pf[j];
            }
        }
        __syncthreads();
        // issue loads for chunk+2 (a full 16-step chunk of slack)
        if (sic == CH - 1 && step + CH + 1 < SS) {
            const int nchunk = (step >> 4) + 2;
#pragma unroll
            for (int j = 0; j < 3; ++j) {
                const int flat4 = j * 512 + tid;
                const int sc = flat4 / 96, w4 = flat4 % 96;
                const int st2 = nchunk * CH + sc;
                const int s2 = dir ? (SS - 1 - st2) : st2;
                pf[j] = *reinterpret_cast<const float4*>(xg_bd + (size_t)s2 * 768 + w4 * 4);
            }
        }
    }
}

// ---------------------------------------------------------------------------
// Kernel 4: time attention (conv2 + softmax over S) + context + linear+softmax.
// One block per batch item.
// ---------------------------------------------------------------------------
__global__ __launch_bounds__(256) void k_attn2(
    const float* __restrict__ states,   // [B*S, 256]
    const float* __restrict__ c2w,      // [3, 256]
    const float* __restrict__ c2b,      // [3]
    const float* __restrict__ demoip,   // [B, 3]
    const float* __restrict__ lin_w,    // [2, 771]
    const float* __restrict__ lin_b,    // [2]
    float* __restrict__ out,            // [B, 2]
    float* __restrict__ alpha_out,      // [B, 3, 128]
    float* __restrict__ ctx_out)        // [B, 768]
{
    const int b    = blockIdx.x;
    const int t    = threadIdx.x;
    const int lane = t & 63;
    const int wv   = t >> 6;

    __shared__ float sc[NF * SS];
    __shared__ float al[NF * SS];
    __shared__ float ctx[768];
    __shared__ float lo[2];

    const float* st = states + (size_t)b * SS * 256;

    // phase 1: alpha_scores[f][s]
    for (int o = t; o < NF * SS; o += 256) {
        const int f = o >> 7, s = o & 127;
        const float* row  = st + (size_t)s * 256;
        const float* wrow = c2w + f * 256;
        float a = 0.f;
#pragma unroll 8
        for (int h = 0; h < 256; ++h) a += row[h] * wrow[h];
        sc[o] = a + c2b[f];
    }
    __syncthreads();

    // phase 2: softmax over s per filter (waves 0..2)
    if (wv < NF) {
        const float v0 = sc[wv * SS + lane], v1 = sc[wv * SS + 64 + lane];
        float mx = fmaxf(v0, v1);
#pragma unroll
        for (int m = 32; m >= 1; m >>= 1) mx = fmaxf(mx, __shfl_xor(mx, m));
        const float e0 = __expf(v0 - mx), e1 = __expf(v1 - mx);
        float sm = e0 + e1;
#pragma unroll
        for (int m = 32; m >= 1; m >>= 1) sm += __shfl_xor(sm, m);
        const float r = 1.f / sm;
        al[wv * SS + lane]      = e0 * r;
        al[wv * SS + 64 + lane] = e1 * r;
        alpha_out[((size_t)b * NF + wv) * SS + lane]      = e0 * r;
        alpha_out[((size_t)b * NF + wv) * SS + 64 + lane] = e1 * r;
    }
    __syncthreads();

    // phase 3: context[f][h], thread t = h
    float c0 = 0.f, c1 = 0.f, c2 = 0.f;
#pragma unroll 4
    for (int s = 0; s < SS; ++s) {
        const float sv = st[(size_t)s * 256 + t];
        c0 += al[s] * sv;
        c1 += al[SS + s] * sv;
        c2 += al[2 * SS + s] * sv;
    }
    ctx[t]       = c0;
    ctx[256 + t] = c1;
    ctx[512 + t] = c2;
    ctx_out[(size_t)b * 768 + t]       = c0;
    ctx_out[(size_t)b * 768 + 256 + t] = c1;
    ctx_out[(size_t)b * 768 + 512 + t] = c2;
    __syncthreads();

    // phase 4: final linear (771 -> 2) + softmax
    if (t < 2) {
        float a = lin_b[t];
        const float* lw = lin_w + (size_t)t * 771;
#pragma unroll 8
        for (int i = 0; i < 768; ++i) a += ctx[i] * lw[i];
        for (int k = 0; k < 3; ++k) a += demoip[b * 3 + k] * lw[768 + k];
        lo[t] = a;
    }
    __syncthreads();
    if (t == 0) {
        const float m  = fmaxf(lo[0], lo[1]);
        const float e0 = __expf(lo[0] - m), e1 = __expf(lo[1] - m);
        const float s  = e0 + e1;
        out[b * 2 + 0] = e0 / s;
        out[b * 2 + 1] = e1 / s;
    }
}

// ---------------------------------------------------------------------------
extern "C" void kernel_launch(void* const* d_in, const int* in_sizes, int n_in,
                              void* d_out, int out_size, void* d_ws, size_t ws_size,
                              hipStream_t stream) {
    const float* inp     = (const float*)d_in[0];
    const float* demoip  = (const float*)d_in[1];
    const float* conv_w  = (const float*)d_in[2];
    const float* conv_b  = (const float*)d_in[3];
    const float* c2w     = (const float*)d_in[4];
    const float* c2b     = (const float*)d_in[5];
    const float* Wih_f   = (const float*)d_in[6];
    const float* Whh_f   = (const float*)d_in[7];
    const float* bih_f   = (const float*)d_in[8];
    const float* bhh_f   = (const float*)d_in[9];
    const float* Wih_b   = (const float*)d_in[10];
    const float* Whh_b   = (const float*)d_in[11];
    const float* bih_b   = (const float*)d_in[12];
    const float* bhh_b   = (const float*)d_in[13];
    const float* lin_w   = (const float*)d_in[14];
    const float* lin_b   = (const float*)d_in[15];

    // d_out layout: out[64] | alpha[12288] | states[1048576] | context[24576] | conv_wts[262144]
    float* out      = (float*)d_out;
    float* alpha    = out + 64;
    float* states   = out + 12352;
    float* context  = out + 1060928;
    float* conv_wts = out + 1085504;

    // workspace: conv_out [4096*256] | xg [4096*768]  (16 MiB total)
    float* conv_out = (float*)d_ws;
    float* xg       = conv_out + (size_t)4096 * 256;

    k_pool<<<dim3(BB * SS), dim3(256), 0, stream>>>(inp, conv_w, conv_b, conv_out, conv_wts);
    k_xg<<<dim3(4096 / GBM, 768 / GBN), dim3(256), 0, stream>>>(conv_out, Wih_f, Wih_b, bih_f, bih_b, xg);
    k_gru<<<dim3(64), dim3(512), 0, stream>>>(xg, Whh_f, Whh_b, bhh_f, bhh_b, states);
    k_attn2<<<dim3(BB), dim3(256), 0, stream>>>(states, c2w, c2b, demoip, lin_w, lin_b, out, alpha, context);
}